// Round 1
// baseline (4566.023 us; speedup 1.0000x reference)
//
#include <hip/hip_runtime.h>
#include <math.h>

// StressCapsuleLayer: capsule dynamic routing (3 iters), fused recompute design.
//   x [128][648][16] f32, W [648][32][32][16] f32 -> v [128][32][32] f32
//
// 3 passes over (b,n); u_hat[b,n,j,:] recomputed each pass (never materialized).
//   pass0: c = 1/32 exactly            -> s0 -> v0 = squash(s0)
//   pass1: logit = <u_hat, v0>         -> softmax_j -> s1 -> v1
//   pass2: logit = <u,v0> + <u,v1>     -> softmax_j -> s2 -> v2 = output
// Lane mapping: one wave handles one full (b,n) row: j = lane&31, dblk = lane>>5,
// k = 0..15 (d = dblk*16+k). Agreement reduce = shfl_xor(32); softmax = width-32
// butterflies. W[n] staged to LDS (j-innermost transpose) via global_load_lds
// with pre-swizzled per-lane SOURCE + linear dest (rule #21) so the hot
// ds_read_b128 is 64-lane contiguous (conflict-free).

#define N_IN 648
#define NB 4              // n per block
#define BCH 16            // b per block (4 waves x 4 b)
#define NCHUNKS (N_IN / NB)   // 162
#define BCHUNKS 8             // 128 / 16

#define GLDS(gsrc, ldst)                                                        \
  __builtin_amdgcn_global_load_lds(                                             \
      (const __attribute__((address_space(1))) void*)(gsrc),                    \
      (__attribute__((address_space(3))) void*)(ldst), 16, 0, 0)

template <int PHASE>
__global__ __launch_bounds__(256, 2) void caps_pass(
    const float* __restrict__ x,   // [128][648][16]
    const float* __restrict__ W,   // [648][32][32][16]
    const float* __restrict__ v0,  // [128][32][32]  (PHASE>=1)
    const float* __restrict__ v1,  // [128][32][32]  (PHASE==2)
    float* __restrict__ s_out)     // [128][32][32]  atomic-accumulated (pre-zeroed)
{
  __shared__ float4 wlds[4096];  // 64KB: W[n], chunk c = (k*4+q)*64 + (dblk*32+j)

  const int t = threadIdx.x;
  const int w = t >> 6;   // wave 0..3
  const int l = t & 63;   // lane
  const int j = l & 31;
  const int dblk = l >> 5;

  const int n0 = blockIdx.x * NB;
  const int b0 = blockIdx.y * BCH;

  float s_acc[4][16];
#pragma unroll
  for (int bb = 0; bb < 4; ++bb)
#pragma unroll
    for (int k = 0; k < 16; ++k) s_acc[bb][k] = 0.f;

  for (int nn = 0; nn < NB; ++nn) {
    const int n = n0 + nn;
    const float4* Wn = (const float4*)(W + (size_t)n * 16384);

    __syncthreads();  // previous iteration's LDS reads complete
#pragma unroll
    for (int r = 0; r < 16; ++r) {
      // physical chunk p = r*256 + t lands at lds + p*16 (linear dest).
      // source quad g = inverse of c(g) = ((k*4+q)*2 + dblk)*32 + j.
      const int p = r * 256 + t;
      const int jj = p & 31;
      const int tt = p >> 5;
      const int db = tt & 1;
      const int kq = tt >> 1;
      const int g = jj * 128 + ((db * 16 + (kq >> 2)) << 2) + (kq & 3);
      GLDS(Wn + g, (char*)wlds + r * 4096 + w * 1024);
    }
    __syncthreads();  // staging drained (vmcnt(0) before barrier)

#pragma unroll
    for (int bbp = 0; bbp < 2; ++bbp) {
      float u[2][16];
      float xx[2][16];
#pragma unroll
      for (int h = 0; h < 2; ++h) {
        const int b = b0 + w * 4 + bbp * 2 + h;
        const float4* xp = (const float4*)(x + ((size_t)b * N_IN + n) * 16);
#pragma unroll
        for (int q = 0; q < 4; ++q) {
          const float4 xv = xp[q];  // broadcast load (all lanes same addr)
          xx[h][q * 4 + 0] = xv.x;
          xx[h][q * 4 + 1] = xv.y;
          xx[h][q * 4 + 2] = xv.z;
          xx[h][q * 4 + 3] = xv.w;
        }
      }
#pragma unroll
      for (int k = 0; k < 16; ++k) {
        u[0][k] = 0.f;
        u[1][k] = 0.f;
      }
#pragma unroll
      for (int kq = 0; kq < 64; ++kq) {
        const int k = kq >> 2, q = kq & 3;
        const float4 wv = wlds[kq * 64 + l];  // 64-lane contiguous, conflict-free
        u[0][k] = fmaf(wv.x, xx[0][q * 4 + 0], u[0][k]);
        u[0][k] = fmaf(wv.y, xx[0][q * 4 + 1], u[0][k]);
        u[0][k] = fmaf(wv.z, xx[0][q * 4 + 2], u[0][k]);
        u[0][k] = fmaf(wv.w, xx[0][q * 4 + 3], u[0][k]);
        u[1][k] = fmaf(wv.x, xx[1][q * 4 + 0], u[1][k]);
        u[1][k] = fmaf(wv.y, xx[1][q * 4 + 1], u[1][k]);
        u[1][k] = fmaf(wv.z, xx[1][q * 4 + 2], u[1][k]);
        u[1][k] = fmaf(wv.w, xx[1][q * 4 + 3], u[1][k]);
      }

#pragma unroll
      for (int h = 0; h < 2; ++h) {
        const int bb = bbp * 2 + h;
        const int b = b0 + w * 4 + bb;
        float c;
        if (PHASE == 0) {
          c = 1.0f / 32.0f;  // softmax(zeros) exactly
        } else {
          float logit = 0.f;
          {
            const float4* vp = (const float4*)(v0 + (size_t)b * 1024 + j * 32 + dblk * 16);
            float a = 0.f;
#pragma unroll
            for (int q = 0; q < 4; ++q) {
              const float4 vv = vp[q];
              a = fmaf(u[h][q * 4 + 0], vv.x, a);
              a = fmaf(u[h][q * 4 + 1], vv.y, a);
              a = fmaf(u[h][q * 4 + 2], vv.z, a);
              a = fmaf(u[h][q * 4 + 3], vv.w, a);
            }
            logit += a;
          }
          if (PHASE == 2) {
            const float4* vp = (const float4*)(v1 + (size_t)b * 1024 + j * 32 + dblk * 16);
            float a = 0.f;
#pragma unroll
            for (int q = 0; q < 4; ++q) {
              const float4 vv = vp[q];
              a = fmaf(u[h][q * 4 + 0], vv.x, a);
              a = fmaf(u[h][q * 4 + 1], vv.y, a);
              a = fmaf(u[h][q * 4 + 2], vv.z, a);
              a = fmaf(u[h][q * 4 + 3], vv.w, a);
            }
            logit += a;
          }
          // full agreement over d: combine the two d-halves
          logit += __shfl_xor(logit, 32);
          // softmax over 32 j's (width-32 butterflies; halves are identical)
          float m = logit;
#pragma unroll
          for (int off = 16; off >= 1; off >>= 1) m = fmaxf(m, __shfl_xor(m, off));
          const float e = __expf(logit - m);
          float Z = e;
#pragma unroll
          for (int off = 16; off >= 1; off >>= 1) Z += __shfl_xor(Z, off);
          c = e / Z;
        }
#pragma unroll
        for (int k = 0; k < 16; ++k) s_acc[bb][k] = fmaf(c, u[h][k], s_acc[bb][k]);
      }
    }
  }

  // accumulate partial s into global (fp32 atomics; threshold-checked fp order)
#pragma unroll
  for (int bb = 0; bb < 4; ++bb) {
    const int b = b0 + w * 4 + bb;
    float* sp = s_out + (size_t)b * 1024 + j * 32 + dblk * 16;
#pragma unroll
    for (int k = 0; k < 16; ++k) atomicAdd(sp + k, s_acc[bb][k]);
  }
}

// squash: v = s * (|s|^2 / (1+|s|^2)) / sqrt(|s|^2 + 1e-7), norm over last dim (32)
__global__ void squash_kernel(const float* __restrict__ s, float* __restrict__ v) {
  const int e = blockIdx.x * 256 + threadIdx.x;  // 131072 elems, rows of 32 align to half-waves
  const float val = s[e];
  float s2 = val * val;
#pragma unroll
  for (int off = 16; off >= 1; off >>= 1) s2 += __shfl_xor(s2, off);
  const float scale = (s2 / (1.0f + s2)) * rsqrtf(s2 + 1e-7f);
  v[e] = val * scale;
}

extern "C" void kernel_launch(void* const* d_in, const int* in_sizes, int n_in,
                              void* d_out, int out_size, void* d_ws, size_t ws_size,
                              hipStream_t stream) {
  const float* x = (const float*)d_in[0];
  const float* W = (const float*)d_in[1];
  float* out = (float*)d_out;

  float* s_ws = (float*)d_ws;      // 131072 f32
  float* v0 = s_ws + 131072;       // 131072 f32
  float* v1 = v0 + 131072;         // 131072 f32

  const dim3 grid(NCHUNKS, BCHUNKS);
  const dim3 blk(256);

  hipMemsetAsync(s_ws, 0, 131072 * sizeof(float), stream);
  caps_pass<0><<<grid, blk, 0, stream>>>(x, W, nullptr, nullptr, s_ws);
  squash_kernel<<<512, 256, 0, stream>>>(s_ws, v0);

  hipMemsetAsync(s_ws, 0, 131072 * sizeof(float), stream);
  caps_pass<1><<<grid, blk, 0, stream>>>(x, W, v0, nullptr, s_ws);
  squash_kernel<<<512, 256, 0, stream>>>(s_ws, v1);

  hipMemsetAsync(s_ws, 0, 131072 * sizeof(float), stream);
  caps_pass<2><<<grid, blk, 0, stream>>>(x, W, v0, v1, s_ws);
  squash_kernel<<<512, 256, 0, stream>>>(s_ws, out);
}

// Round 2
// 971.669 us; speedup vs baseline: 4.6992x; 4.6992x over previous
//
#include <hip/hip_runtime.h>
#include <math.h>

// StressCapsuleLayer: capsule dynamic routing (3 iters), fused recompute design.
//   x [128][648][16] f32, W [648][32][32][16] f32 -> v [128][32][32] f32
//
// 3 passes over (b,n); u_hat[b,n,j,:] recomputed each pass (never materialized).
//   pass0: c = 1/32 exactly            -> s0 -> v0 = squash(s0)
//   pass1: logit = <u_hat, v0>         -> softmax_j -> s1 -> v1
//   pass2: logit = <u,v0> + <u,v1>     -> softmax_j -> s2 -> v2 = output
//
// R1 change: atomics were the bottleneck (800MB WRITE_SIZE/pass, 1700us/pass,
// VALUBusy 1.6% -- 21M device-scope fp32 atomicAdds with 162-way per-address
// contention serialize at the memory side). Replaced with a deterministic
// two-stage reduction: stage A writes disjoint per-n-chunk partials to d_ws
// (plain stores), stage B sums NC partials and fuses the squash. NC chosen
// from ws_size via divisor ladder (deterministic; prefers 81 -> 648 blocks).

#define N_IN 648
#define BCH 16            // b per block (4 waves x 4 b)
#define ELEMS 131072      // 128*32*32 output elements

#define GLDS(gsrc, ldst)                                                        \
  __builtin_amdgcn_global_load_lds(                                             \
      (const __attribute__((address_space(1))) void*)(gsrc),                    \
      (__attribute__((address_space(3))) void*)(ldst), 16, 0, 0)

template <int PHASE>
__global__ __launch_bounds__(256, 2) void caps_pass(
    const float* __restrict__ x,     // [128][648][16]
    const float* __restrict__ W,     // [648][32][32][16]
    const float* __restrict__ v0,    // [128][32][32]  (PHASE>=1)
    const float* __restrict__ v1,    // [128][32][32]  (PHASE==2)
    float* __restrict__ parts,       // [NC][128][32][32] disjoint partial sums
    int nPer)                        // n's per block (648 / NC)
{
  __shared__ float4 wlds[4096];  // 64KB: W[n], chunk c = (k*4+q)*64 + (dblk*32+j)

  const int t = threadIdx.x;
  const int w = t >> 6;   // wave 0..3
  const int l = t & 63;   // lane
  const int j = l & 31;
  const int dblk = l >> 5;

  const int n0 = blockIdx.x * nPer;
  const int b0 = blockIdx.y * BCH;

  float s_acc[4][16];
#pragma unroll
  for (int bb = 0; bb < 4; ++bb)
#pragma unroll
    for (int k = 0; k < 16; ++k) s_acc[bb][k] = 0.f;

  for (int nn = 0; nn < nPer; ++nn) {
    const int n = n0 + nn;
    const float4* Wn = (const float4*)(W + (size_t)n * 16384);

    __syncthreads();  // previous iteration's LDS reads complete
#pragma unroll
    for (int r = 0; r < 16; ++r) {
      // physical chunk p = r*256 + t lands at lds + p*16 (linear dest).
      // source quad g = inverse of c(g) = ((k*4+q)*2 + dblk)*32 + j.
      const int p = r * 256 + t;
      const int jj = p & 31;
      const int tt = p >> 5;
      const int db = tt & 1;
      const int kq = tt >> 1;
      const int g = jj * 128 + ((db * 16 + (kq >> 2)) << 2) + (kq & 3);
      GLDS(Wn + g, (char*)wlds + r * 4096 + w * 1024);
    }
    __syncthreads();  // staging drained (vmcnt(0) before barrier)

#pragma unroll
    for (int bbp = 0; bbp < 2; ++bbp) {
      float u[2][16];
      float xx[2][16];
#pragma unroll
      for (int h = 0; h < 2; ++h) {
        const int b = b0 + w * 4 + bbp * 2 + h;
        const float4* xp = (const float4*)(x + ((size_t)b * N_IN + n) * 16);
#pragma unroll
        for (int q = 0; q < 4; ++q) {
          const float4 xv = xp[q];  // broadcast load (all lanes same addr)
          xx[h][q * 4 + 0] = xv.x;
          xx[h][q * 4 + 1] = xv.y;
          xx[h][q * 4 + 2] = xv.z;
          xx[h][q * 4 + 3] = xv.w;
        }
      }
#pragma unroll
      for (int k = 0; k < 16; ++k) {
        u[0][k] = 0.f;
        u[1][k] = 0.f;
      }
#pragma unroll
      for (int kq = 0; kq < 64; ++kq) {
        const int k = kq >> 2, q = kq & 3;
        const float4 wv = wlds[kq * 64 + l];  // 64-lane contiguous, conflict-free
        u[0][k] = fmaf(wv.x, xx[0][q * 4 + 0], u[0][k]);
        u[0][k] = fmaf(wv.y, xx[0][q * 4 + 1], u[0][k]);
        u[0][k] = fmaf(wv.z, xx[0][q * 4 + 2], u[0][k]);
        u[0][k] = fmaf(wv.w, xx[0][q * 4 + 3], u[0][k]);
        u[1][k] = fmaf(wv.x, xx[1][q * 4 + 0], u[1][k]);
        u[1][k] = fmaf(wv.y, xx[1][q * 4 + 1], u[1][k]);
        u[1][k] = fmaf(wv.z, xx[1][q * 4 + 2], u[1][k]);
        u[1][k] = fmaf(wv.w, xx[1][q * 4 + 3], u[1][k]);
      }

#pragma unroll
      for (int h = 0; h < 2; ++h) {
        const int bb = bbp * 2 + h;
        const int b = b0 + w * 4 + bb;
        float c;
        if (PHASE == 0) {
          c = 1.0f / 32.0f;  // softmax(zeros) exactly
        } else {
          float logit = 0.f;
          {
            const float4* vp = (const float4*)(v0 + (size_t)b * 1024 + j * 32 + dblk * 16);
            float a = 0.f;
#pragma unroll
            for (int q = 0; q < 4; ++q) {
              const float4 vv = vp[q];
              a = fmaf(u[h][q * 4 + 0], vv.x, a);
              a = fmaf(u[h][q * 4 + 1], vv.y, a);
              a = fmaf(u[h][q * 4 + 2], vv.z, a);
              a = fmaf(u[h][q * 4 + 3], vv.w, a);
            }
            logit += a;
          }
          if (PHASE == 2) {
            const float4* vp = (const float4*)(v1 + (size_t)b * 1024 + j * 32 + dblk * 16);
            float a = 0.f;
#pragma unroll
            for (int q = 0; q < 4; ++q) {
              const float4 vv = vp[q];
              a = fmaf(u[h][q * 4 + 0], vv.x, a);
              a = fmaf(u[h][q * 4 + 1], vv.y, a);
              a = fmaf(u[h][q * 4 + 2], vv.z, a);
              a = fmaf(u[h][q * 4 + 3], vv.w, a);
            }
            logit += a;
          }
          // full agreement over d: combine the two d-halves
          logit += __shfl_xor(logit, 32);
          // softmax over 32 j's (width-32 butterflies; halves are identical)
          float m = logit;
#pragma unroll
          for (int off = 16; off >= 1; off >>= 1) m = fmaxf(m, __shfl_xor(m, off));
          const float e = __expf(logit - m);
          float Z = e;
#pragma unroll
          for (int off = 16; off >= 1; off >>= 1) Z += __shfl_xor(Z, off);
          c = e / Z;
        }
#pragma unroll
        for (int k = 0; k < 16; ++k) s_acc[bb][k] = fmaf(c, u[h][k], s_acc[bb][k]);
      }
    }
  }

  // disjoint partial store: parts[chunk][b][j][d] -- no atomics, no contention
  float* pbase = parts + (size_t)blockIdx.x * ELEMS;
#pragma unroll
  for (int bb = 0; bb < 4; ++bb) {
    const int b = b0 + w * 4 + bb;
    float* sp = pbase + (size_t)b * 1024 + j * 32 + dblk * 16;
#pragma unroll
    for (int k = 0; k < 16; ++k) sp[k] = s_acc[bb][k];
  }
}

// stage B: sum NC partials, then squash over last dim (32) via width-32 shuffle
__global__ void reduce_squash(const float* __restrict__ parts, int NC,
                              float* __restrict__ v) {
  const int e = blockIdx.x * 256 + threadIdx.x;  // rows of 32 align to half-waves
  float s = 0.f;
  for (int c = 0; c < NC; ++c) s += parts[(size_t)c * ELEMS + e];
  float s2 = s * s;
#pragma unroll
  for (int off = 16; off >= 1; off >>= 1) s2 += __shfl_xor(s2, off);
  const float scale = (s2 / (1.0f + s2)) * rsqrtf(s2 + 1e-7f);
  v[e] = s * scale;
}

extern "C" void kernel_launch(void* const* d_in, const int* in_sizes, int n_in,
                              void* d_out, int out_size, void* d_ws, size_t ws_size,
                              hipStream_t stream) {
  const float* x = (const float*)d_in[0];
  const float* W = (const float*)d_in[1];
  float* out = (float*)d_out;

  float* v0 = (float*)d_ws;            // 131072 f32
  float* v1 = v0 + ELEMS;              // 131072 f32
  float* parts = v1 + ELEMS;           // NC * 131072 f32

  // choose NC (divisor of 648) from available workspace; deterministic since
  // ws_size is fixed across calls.
  int avail = 0;
  if (ws_size / 4 > 2 * (size_t)ELEMS)
    avail = (int)((ws_size / 4 - 2 * (size_t)ELEMS) / ELEMS);
  const int ladder[] = {81, 54, 27, 24, 18, 12, 9, 8, 6, 4, 3, 2, 1};
  int NC = 1;
  for (int i = 0; i < 13; ++i)
    if (ladder[i] <= avail) { NC = ladder[i]; break; }
  const int nPer = N_IN / NC;

  const dim3 grid(NC, 8);
  const dim3 blk(256);

  caps_pass<0><<<grid, blk, 0, stream>>>(x, W, nullptr, nullptr, parts, nPer);
  reduce_squash<<<512, 256, 0, stream>>>(parts, NC, v0);

  caps_pass<1><<<grid, blk, 0, stream>>>(x, W, v0, nullptr, parts, nPer);
  reduce_squash<<<512, 256, 0, stream>>>(parts, NC, v1);

  caps_pass<2><<<grid, blk, 0, stream>>>(x, W, v0, v1, parts, nPer);
  reduce_squash<<<512, 256, 0, stream>>>(parts, NC, out);
}